// Round 3
// baseline (109.065 us; speedup 1.0000x reference)
//
#include <hip/hip_runtime.h>
#include <cstdint>
#include <cstddef>

typedef unsigned short us;
using short8 = __attribute__((ext_vector_type(8))) short;  // 8 bf16
using f32x4  = __attribute__((ext_vector_type(4))) float;

union U8 { us u[8]; short8 v; };

#define MFMA16(a,b,c) __builtin_amdgcn_mfma_f32_16x16x32_bf16((a),(b),(c),0,0,0)

static __device__ __forceinline__ us f2bf(float f){
  union { float f; unsigned u; } cv; cv.f = f;
  unsigned u = cv.u;
  return (us)((u + 0x7fffu + ((u >> 16) & 1u)) >> 16);
}

typedef const __attribute__((address_space(1))) void* gp_t;
typedef __attribute__((address_space(3))) void* lp_t;
#define GL16(g,l) __builtin_amdgcn_global_load_lds((gp_t)(g),(lp_t)(l),16,0,0)

// ---------------------------------------------------------------------------
// Convert fp32 inputs to bf16.  x tensors reordered [n][b][c] -> [b*1024+n][c].
// ---------------------------------------------------------------------------
__global__ __launch_bounds__(256) void convert_all(
    const float* __restrict__ xq, const float* __restrict__ xk, const float* __restrict__ xv,
    const float* __restrict__ Wq, const float* __restrict__ Wk,
    const float* __restrict__ Wv, const float* __restrict__ Wo,
    us* __restrict__ xbq, us* __restrict__ xbk, us* __restrict__ xbv,
    us* __restrict__ wb)
{
  unsigned id = blockIdx.x * 256u + threadIdx.x;
  const float* src; us* dst;
  if (id < 1179648u){                      // 3 * 4096 * 96
    unsigned z  = id / 393216u;
    unsigned rr = id - z * 393216u;
    unsigned row = rr / 96u, cc = rr - row * 96u;
    unsigned bsel = row >> 10, n = row & 1023u;
    const float* x = (z == 0) ? xq : (z == 1) ? xk : xv;
    us* xb = (z == 0) ? xbq : (z == 1) ? xbk : xbv;
    src = x  + (size_t)(n * 4u + bsel) * 768u + cc * 8u;
    dst = xb + (size_t)row * 768u + cc * 8u;
  } else {                                 // 4 * 73728 W chunks
    unsigned wi = id - 1179648u;
    unsigned z  = wi / 73728u;
    unsigned rr = wi - z * 73728u;
    const float* W = (z == 0) ? Wq : (z == 1) ? Wk : (z == 2) ? Wv : Wo;
    src = W  + (size_t)rr * 8u;
    dst = wb + (size_t)z * 589824u + rr * 8u;
  }
  f32x4 a = *(const f32x4*)src;
  f32x4 b = *(const f32x4*)(src + 4);
  U8 o;
#pragma unroll
  for (int j = 0; j < 4; ++j){ o.u[j] = f2bf(a[j]); o.u[4 + j] = f2bf(b[j]); }
  *(short8*)dst = o.v;
}

// ---------------------------------------------------------------------------
// Mask compaction: per batch b, rank[n] = position among unmasked keys (-1 if
// masked), nb[b] = count.  Zeroes kc pad rows / vtc pad cols in [nb, ceil64),
// and writes pre-scaled pad mask table maskc (0 for valid, -1.25e29 for pad).
// ---------------------------------------------------------------------------
__global__ __launch_bounds__(256) void compact_idx(
    const int* __restrict__ mask, int* __restrict__ rank, int* __restrict__ nbd,
    float* __restrict__ maskc, us* __restrict__ kc, us* __restrict__ vtc)
{
  const int b = blockIdx.x, tid = threadIdx.x, lane = tid & 63, w = tid >> 6;
  __shared__ int wsum[4];

  int m[4], cnt = 0;
#pragma unroll
  for (int j = 0; j < 4; ++j){
    m[j] = mask[b * 1024 + tid * 4 + j] ? 0 : 1;
    cnt += m[j];
  }
  // inclusive wave scan of cnt
  int sc = cnt;
#pragma unroll
  for (int off = 1; off < 64; off <<= 1){
    int t = __shfl_up(sc, off, 64);
    if (lane >= off) sc += t;
  }
  if (lane == 63) wsum[w] = sc;
  __syncthreads();
  int woff = 0;
#pragma unroll
  for (int i = 0; i < 4; ++i) if (i < w) woff += wsum[i];
  const int total = wsum[0] + wsum[1] + wsum[2] + wsum[3];
  int rr = woff + sc - cnt;                 // exclusive prefix for this thread
#pragma unroll
  for (int j = 0; j < 4; ++j){
    rank[b * 1024 + tid * 4 + j] = m[j] ? rr : -1;
    rr += m[j];
  }
  if (tid == 0) nbd[b] = total;

  const int ceil64 = (total + 63) & ~63;
  for (int j = tid; j < ceil64; j += 256)
    maskc[b * 1024 + j] = (j < total) ? 0.f : -1.25e29f;

  // zero kc pad rows
  short8 z8 = {};
  for (int r = total + w; r < ceil64; r += 4)
    for (int c = lane; c < 96; c += 64)
      *(short8*)(kc + (size_t)(b * 1024 + r) * 768 + c * 8) = z8;

  // zero vtc pad cols
  for (int r = w; r < 768; r += 4)
    for (int j = total + lane; j < ceil64; j += 64)
      vtc[(size_t)(b * 768 + r) * 1024 + j] = 0;
}

// ---------------------------------------------------------------------------
// QKV projection (m97 structure).  z=0 -> qh [b*1024+n][768];
// z=1 -> kc scatter to compacted rows; z=2 -> vtc scatter [b][h][d][rank].
// ---------------------------------------------------------------------------
__global__ __launch_bounds__(256, 2) void qkv_gemm3(
    const us* __restrict__ xbq, const us* __restrict__ xbk, const us* __restrict__ xbv,
    const us* __restrict__ wb,
    const float* __restrict__ bq, const float* __restrict__ bk, const float* __restrict__ bv,
    const float* __restrict__ zeta, const int* __restrict__ rank,
    us* __restrict__ qh, us* __restrict__ kc, us* __restrict__ vtc)
{
  const int z = blockIdx.z;
  const us* A  = (z == 0) ? xbq : (z == 1) ? xbk : xbv;
  const us* Bw = wb + (size_t)z * 589824;
  const float* bias = (z == 0) ? bq : (z == 1) ? bk : bv;

  __shared__ __align__(16) us As[2][128 * 64];
  __shared__ __align__(16) us Bs[2][128 * 64];

  const int tid = threadIdx.x, lane = tid & 63, w = tid >> 6;
  const int wr = (w >> 1) * 64, wc = (w & 1) * 64;
  const int mt = blockIdx.x, nt = blockIdx.y;

  f32x4 acc[4][4] = {};

  auto STAGE = [&](int kt, int buf){
#pragma unroll
    for (int p = 0; p < 4; ++p){
      int chunk = p * 256 + tid;
      int row = chunk >> 3, colb = (chunk & 7) * 8;
      GL16(A  + (size_t)(mt * 128 + row) * 768 + kt * 64 + colb,
           As[buf] + (p * 256 + w * 64) * 8);
      GL16(Bw + (size_t)(nt * 128 + row) * 768 + kt * 64 + colb,
           Bs[buf] + (p * 256 + w * 64) * 8);
    }
  };

  STAGE(0, 0);
  __syncthreads();
  int cur = 0;
  for (int kt = 0; kt < 12; ++kt){
    if (kt < 11) STAGE(kt + 1, cur ^ 1);
#pragma unroll
    for (int ks = 0; ks < 2; ++ks){
      short8 af[4], bf4[4];
#pragma unroll
      for (int mf = 0; mf < 4; ++mf){
        int row = wr + mf * 16 + (lane & 15);
        af[mf] = *(const short8*)(As[cur] + row * 64 + ks * 32 + (lane >> 4) * 8);
      }
#pragma unroll
      for (int nf = 0; nf < 4; ++nf){
        int row = wc + nf * 16 + (lane & 15);
        bf4[nf] = *(const short8*)(Bs[cur] + row * 64 + ks * 32 + (lane >> 4) * 8);
      }
#pragma unroll
      for (int mf = 0; mf < 4; ++mf)
#pragma unroll
        for (int nf = 0; nf < 4; ++nf)
          acc[mf][nf] = MFMA16(af[mf], bf4[nf], acc[mf][nf]);
    }
    __syncthreads();
    cur ^= 1;
  }

  float bzv[4], zzv[4]; int colv[4];
#pragma unroll
  for (int nf = 0; nf < 4; ++nf){
    colv[nf] = nt * 128 + wc + nf * 16 + (lane & 15);
    bzv[nf] = bias[colv[nf]];
    zzv[nf] = zeta[colv[nf]];
  }

  if (z == 0){
#pragma unroll
    for (int mf = 0; mf < 4; ++mf)
#pragma unroll
      for (int r = 0; r < 4; ++r){
        int row = mt * 128 + wr + mf * 16 + (lane >> 4) * 4 + r;
#pragma unroll
        for (int nf = 0; nf < 4; ++nf)
          qh[(size_t)row * 768 + colv[nf]] = f2bf((acc[mf][nf][r] + bzv[nf]) * zzv[nf]);
      }
  } else {
#pragma unroll
    for (int mf = 0; mf < 4; ++mf)
#pragma unroll
      for (int r = 0; r < 4; ++r){
        int row = mt * 128 + wr + mf * 16 + (lane >> 4) * 4 + r;
        int rk = rank[row];
        if (rk < 0) continue;
        int bsel = row >> 10;
        if (z == 1){
#pragma unroll
          for (int nf = 0; nf < 4; ++nf)
            kc[(size_t)(bsel * 1024 + rk) * 768 + colv[nf]] =
                f2bf((acc[mf][nf][r] + bzv[nf]) * zzv[nf]);
        } else {
#pragma unroll
          for (int nf = 0; nf < 4; ++nf){
            int hh = colv[nf] >> 6, dd = colv[nf] & 63;
            vtc[((size_t)(bsel * 12 + hh) * 64 + dd) * 1024 + rk] =
                f2bf((acc[mf][nf][r] + bzv[nf]) * zzv[nf]);
          }
        }
      }
  }
}

// ---------------------------------------------------------------------------
// Flash attention over COMPACTED keys: nt = ceil(nb[b]/64) tiles (~8-9 vs 16).
// Fixed-reference softmax (m == 0, exact); pad keys get p == 0 via maskc.
// ---------------------------------------------------------------------------
__global__ __launch_bounds__(256) void attn_fwd3(
    const us* __restrict__ qh, const us* __restrict__ kc,
    const us* __restrict__ vtc, const float* __restrict__ maskc,
    const int* __restrict__ nbd, us* __restrict__ ao)
{
  const int qt = blockIdx.x, h = blockIdx.y, b = blockIdx.z;
  const int tid = threadIdx.x, lane = tid & 63, w = tid >> 6;

  const int nbv = nbd[b];
  const int nt = (nbv + 63) >> 6;

  __shared__ __align__(16) us Qs[64 * 64];
  __shared__ __align__(16) us Ks[2][64 * 64];
  __shared__ __align__(16) us Vs[2][64 * 64];
  __shared__ __align__(16) us Ps[64 * 64];
  __shared__ float smask[1024];

#pragma unroll
  for (int i = 0; i < 4; ++i){
    int key = i * 256 + tid;
    smask[key] = (key < nt * 64) ? maskc[b * 1024 + key] : 0.f;
  }
#pragma unroll
  for (int p = 0; p < 2; ++p){
    int c = p * 256 + tid, row = c >> 3, db = (c & 7) * 8;
    short8 qv = *(const short8*)(qh + (size_t)(b * 1024 + qt * 64 + row) * 768 + h * 64 + db);
    *(short8*)((char*)Qs + ((row * 128 + db * 2) ^ ((row & 7) << 4))) = qv;
  }

  short8 kr[2], vr[2];
  auto KVLOAD = [&](int kt){
#pragma unroll
    for (int p = 0; p < 2; ++p){
      int c = p * 256 + tid, row = c >> 3, db = (c & 7) * 8;
      kr[p] = *(const short8*)(kc + (size_t)(b * 1024 + kt * 64 + row) * 768 + h * 64 + db);
      vr[p] = *(const short8*)(vtc + ((size_t)((b * 12 + h) * 64 + row)) * 1024 + kt * 64 + db);
    }
  };
  auto KVWRITE = [&](int buf){
#pragma unroll
    for (int p = 0; p < 2; ++p){
      int c = p * 256 + tid, row = c >> 3, db = (c & 7) * 8;
      int byte = (row * 128 + db * 2) ^ ((row & 7) << 4);
      *(short8*)((char*)Ks[buf] + byte) = kr[p];
      *(short8*)((char*)Vs[buf] + byte) = vr[p];
    }
  };
  KVLOAD(0); KVWRITE(0);
  __syncthreads();

  short8 qf[2];
#pragma unroll
  for (int ks = 0; ks < 2; ++ks){
    int row = w * 16 + (lane & 15);
    qf[ks] = *(const short8*)((const char*)Qs +
              ((row * 128 + ks * 64 + (lane >> 4) * 16) ^ ((row & 7) << 4)));
  }

  float lsum[4] = {0.f, 0.f, 0.f, 0.f};
  f32x4 o[4] = {};
  int cur = 0;
  for (int kt = 0; kt < nt; ++kt){
    if (kt + 1 < nt) KVLOAD(kt + 1);

    // S = Q K^T
    f32x4 s[4] = {};
#pragma unroll
    for (int ks = 0; ks < 2; ++ks)
#pragma unroll
      for (int f = 0; f < 4; ++f){
        int row = f * 16 + (lane & 15);
        short8 kf = *(const short8*)((const char*)Ks[cur] +
                    ((row * 128 + ks * 64 + (lane >> 4) * 16) ^ ((row & 7) << 4)));
        s[f] = MFMA16(qf[ks], kf, s[f]);
      }

    float mads[4];
#pragma unroll
    for (int f = 0; f < 4; ++f) mads[f] = smask[kt * 64 + f * 16 + (lane & 15)];
    float p_[4][4];
#pragma unroll
    for (int r = 0; r < 4; ++r){
#pragma unroll
      for (int f = 0; f < 4; ++f) p_[f][r] = __expf(fmaf(s[f][r], 0.125f, mads[f]));
      lsum[r] += (p_[0][r] + p_[1][r]) + (p_[2][r] + p_[3][r]);
    }

#pragma unroll
    for (int f = 0; f < 4; ++f)
#pragma unroll
      for (int r = 0; r < 4; ++r){
        int row = w * 16 + (lane >> 4) * 4 + r;
        *(us*)((char*)Ps + ((row * 128 + (f * 16 + (lane & 15)) * 2) ^ ((row & 7) << 4))) =
            f2bf(p_[f][r]);
      }

#pragma unroll
    for (int ks = 0; ks < 2; ++ks){
      int prow = w * 16 + (lane & 15);
      short8 pa = *(const short8*)((const char*)Ps +
                  ((prow * 128 + ks * 64 + (lane >> 4) * 16) ^ ((prow & 7) << 4)));
#pragma unroll
      for (int df = 0; df < 4; ++df){
        int vrow = df * 16 + (lane & 15);
        short8 vb = *(const short8*)((const char*)Vs[cur] +
                    ((vrow * 128 + ks * 64 + (lane >> 4) * 16) ^ ((vrow & 7) << 4)));
        o[df] = MFMA16(pa, vb, o[df]);
      }
    }

    if (kt + 1 < nt) KVWRITE(cur ^ 1);
    __syncthreads();
    cur ^= 1;
  }

  float linv[4];
#pragma unroll
  for (int r = 0; r < 4; ++r){
    float l = lsum[r];
    l += __shfl_xor(l, 1, 64); l += __shfl_xor(l, 2, 64);
    l += __shfl_xor(l, 4, 64); l += __shfl_xor(l, 8, 64);
    linv[r] = __builtin_amdgcn_rcpf(l);
  }
#pragma unroll
  for (int df = 0; df < 4; ++df)
#pragma unroll
    for (int r = 0; r < 4; ++r){
      int qrow = qt * 64 + w * 16 + (lane >> 4) * 4 + r;
      int dcol = df * 16 + (lane & 15);
      ao[(size_t)(b * 1024 + qrow) * 768 + h * 64 + dcol] = f2bf(o[df][r] * linv[r]);
    }
}

// ---------------------------------------------------------------------------
// Output projection (m97 structure), fp32 output scattered to [n][b][c].
// ---------------------------------------------------------------------------
__global__ __launch_bounds__(256, 2) void out_gemm2(
    const us* __restrict__ ain, const us* __restrict__ wo,
    const float* __restrict__ bo, float* __restrict__ dout)
{
  __shared__ __align__(16) us As[2][128 * 64];
  __shared__ __align__(16) us Bs[2][128 * 64];

  const int tid = threadIdx.x, lane = tid & 63, w = tid >> 6;
  const int wr = (w >> 1) * 64, wc = (w & 1) * 64;
  const int mt = blockIdx.x, nt = blockIdx.y;

  f32x4 acc[4][4] = {};

  auto STAGE = [&](int kt, int buf){
#pragma unroll
    for (int p = 0; p < 4; ++p){
      int chunk = p * 256 + tid;
      int row = chunk >> 3, colb = (chunk & 7) * 8;
      GL16(ain + (size_t)(mt * 128 + row) * 768 + kt * 64 + colb,
           As[buf] + (p * 256 + w * 64) * 8);
      GL16(wo  + (size_t)(nt * 128 + row) * 768 + kt * 64 + colb,
           Bs[buf] + (p * 256 + w * 64) * 8);
    }
  };

  STAGE(0, 0);
  __syncthreads();
  int cur = 0;
  for (int kt = 0; kt < 12; ++kt){
    if (kt < 11) STAGE(kt + 1, cur ^ 1);
#pragma unroll
    for (int ks = 0; ks < 2; ++ks){
      short8 af[4], bf4[4];
#pragma unroll
      for (int mf = 0; mf < 4; ++mf){
        int row = wr + mf * 16 + (lane & 15);
        af[mf] = *(const short8*)(As[cur] + row * 64 + ks * 32 + (lane >> 4) * 8);
      }
#pragma unroll
      for (int nf = 0; nf < 4; ++nf){
        int row = wc + nf * 16 + (lane & 15);
        bf4[nf] = *(const short8*)(Bs[cur] + row * 64 + ks * 32 + (lane >> 4) * 8);
      }
#pragma unroll
      for (int mf = 0; mf < 4; ++mf)
#pragma unroll
        for (int nf = 0; nf < 4; ++nf)
          acc[mf][nf] = MFMA16(af[mf], bf4[nf], acc[mf][nf]);
    }
    __syncthreads();
    cur ^= 1;
  }

#pragma unroll
  for (int nf = 0; nf < 4; ++nf){
    int col = nt * 128 + wc + nf * 16 + (lane & 15);
    float bz = bo[col];
#pragma unroll
    for (int mf = 0; mf < 4; ++mf)
#pragma unroll
      for (int r = 0; r < 4; ++r){
        int row = mt * 128 + wr + mf * 16 + (lane >> 4) * 4 + r;
        int n = row & 1023, bsel = row >> 10;
        dout[(size_t)(n * 4 + bsel) * 768 + col] = acc[mf][nf][r] + bz;
      }
  }
}

extern "C" void kernel_launch(void* const* d_in, const int* in_sizes, int n_in,
                              void* d_out, int out_size, void* d_ws, size_t ws_size,
                              hipStream_t stream)
{
  const float* q    = (const float*)d_in[0];
  const float* k    = (const float*)d_in[1];
  const float* v    = (const float*)d_in[2];
  const int*   mask = (const int*)d_in[3];
  const float* Wq   = (const float*)d_in[4];
  const float* bq   = (const float*)d_in[5];
  const float* Wk   = (const float*)d_in[6];
  const float* bk   = (const float*)d_in[7];
  const float* Wv   = (const float*)d_in[8];
  const float* bv   = (const float*)d_in[9];
  const float* Wo   = (const float*)d_in[10];
  const float* bo   = (const float*)d_in[11];
  const float* zeta = (const float*)d_in[12];

  // bf16 x for q/k parked inside d_out (overwritten by final GEMM)
  us* xbq = (us*)d_out;
  us* xbk = xbq + 3145728;
  // workspace layout (≈29.9 MB total)
  us* xbv = (us*)d_ws;
  us* wb  = xbv + 3145728;      // 4 x 768 x 768 bf16 weights
  us* qh  = wb  + 2359296;
  us* kc  = qh  + 3145728;      // compacted K rows [b*1024 + rank][768]
  us* vtc = kc  + 3145728;      // compacted V^T [b][h][d][rank]
  int*   rank  = (int*)(vtc + 3145728);
  int*   nbd   = rank + 4096;
  float* maskc = (float*)(nbd + 4);
  us* ao = xbv;                 // reuse: xbv dead after qkv_gemm3

  convert_all<<<5760, 256, 0, stream>>>(q, k, v, Wq, Wk, Wv, Wo, xbq, xbk, xbv, wb);
  compact_idx<<<4, 256, 0, stream>>>(mask, rank, nbd, maskc, kc, vtc);
  qkv_gemm3<<<dim3(32, 6, 3), 256, 0, stream>>>(xbq, xbk, xbv, wb, bq, bk, bv,
                                                zeta, rank, qh, kc, vtc);
  attn_fwd3<<<dim3(16, 12, 4), 256, 0, stream>>>(qh, kc, vtc, maskc, nbd, ao);
  out_gemm2<<<dim3(32, 6, 1), 256, 0, stream>>>(ao, wb + 3 * 589824, bo, (float*)d_out);
}

// Round 4
// 93.157 us; speedup vs baseline: 1.1708x; 1.1708x over previous
//
#include <hip/hip_runtime.h>
#include <cstdint>
#include <cstddef>

typedef unsigned short us;
using short8 = __attribute__((ext_vector_type(8))) short;  // 8 bf16
using f32x4  = __attribute__((ext_vector_type(4))) float;

union U8 { us u[8]; short8 v; };

#define MFMA16(a,b,c) __builtin_amdgcn_mfma_f32_16x16x32_bf16((a),(b),(c),0,0,0)

static __device__ __forceinline__ us f2bf(float f){
  union { float f; unsigned u; } cv; cv.f = f;
  unsigned u = cv.u;
  return (us)((u + 0x7fffu + ((u >> 16) & 1u)) >> 16);
}

typedef const __attribute__((address_space(1))) void* gp_t;
typedef __attribute__((address_space(3))) void* lp_t;
#define GL16(g,l) __builtin_amdgcn_global_load_lds((gp_t)(g),(lp_t)(l),16,0,0)

// ---------------------------------------------------------------------------
// Convert fp32 inputs to bf16.  x tensors reordered [n][b][c] -> [b*1024+n][c].
// ---------------------------------------------------------------------------
__global__ __launch_bounds__(256) void convert_all(
    const float* __restrict__ xq, const float* __restrict__ xk, const float* __restrict__ xv,
    const float* __restrict__ Wq, const float* __restrict__ Wk,
    const float* __restrict__ Wv, const float* __restrict__ Wo,
    us* __restrict__ xbq, us* __restrict__ xbk, us* __restrict__ xbv,
    us* __restrict__ wb)
{
  unsigned id = blockIdx.x * 256u + threadIdx.x;
  const float* src; us* dst;
  if (id < 1179648u){                      // 3 * 4096 * 96
    unsigned z  = id / 393216u;
    unsigned rr = id - z * 393216u;
    unsigned row = rr / 96u, cc = rr - row * 96u;
    unsigned bsel = row >> 10, n = row & 1023u;
    const float* x = (z == 0) ? xq : (z == 1) ? xk : xv;
    us* xb = (z == 0) ? xbq : (z == 1) ? xbk : xbv;
    src = x  + (size_t)(n * 4u + bsel) * 768u + cc * 8u;
    dst = xb + (size_t)row * 768u + cc * 8u;
  } else {                                 // 4 * 73728 W chunks
    unsigned wi = id - 1179648u;
    unsigned z  = wi / 73728u;
    unsigned rr = wi - z * 73728u;
    const float* W = (z == 0) ? Wq : (z == 1) ? Wk : (z == 2) ? Wv : Wo;
    src = W  + (size_t)rr * 8u;
    dst = wb + (size_t)z * 589824u + rr * 8u;
  }
  f32x4 a = *(const f32x4*)src;
  f32x4 b = *(const f32x4*)(src + 4);
  U8 o;
#pragma unroll
  for (int j = 0; j < 4; ++j){ o.u[j] = f2bf(a[j]); o.u[4 + j] = f2bf(b[j]); }
  *(short8*)dst = o.v;
}

// ---------------------------------------------------------------------------
// Mask compaction (index/mask tables only; pad zeroing is done by memset).
// rank[b][n] = position among unmasked keys (-1 if masked); nb[b] = count;
// maskc[b][j] = 0 for j<nb, -1.25e29 for pad (pre-scaled).
// ---------------------------------------------------------------------------
__global__ __launch_bounds__(256) void compact_idx(
    const int* __restrict__ mask, int* __restrict__ rank, int* __restrict__ nbd,
    float* __restrict__ maskc)
{
  const int b = blockIdx.x, tid = threadIdx.x, lane = tid & 63, w = tid >> 6;
  __shared__ int wsum[4];

  int m[4], cnt = 0;
#pragma unroll
  for (int j = 0; j < 4; ++j){
    m[j] = mask[b * 1024 + tid * 4 + j] ? 0 : 1;
    cnt += m[j];
  }
  int sc = cnt;
#pragma unroll
  for (int off = 1; off < 64; off <<= 1){
    int t = __shfl_up(sc, off, 64);
    if (lane >= off) sc += t;
  }
  if (lane == 63) wsum[w] = sc;
  __syncthreads();
  int woff = 0;
#pragma unroll
  for (int i = 0; i < 4; ++i) if (i < w) woff += wsum[i];
  const int total = wsum[0] + wsum[1] + wsum[2] + wsum[3];
  int rr = woff + sc - cnt;
#pragma unroll
  for (int j = 0; j < 4; ++j){
    rank[b * 1024 + tid * 4 + j] = m[j] ? rr : -1;
    rr += m[j];
  }
  if (tid == 0) nbd[b] = total;

  const int ceil64 = (total + 63) & ~63;
  for (int j = tid; j < ceil64; j += 256)
    maskc[b * 1024 + j] = (j < total) ? 0.f : -1.25e29f;
}

// ---------------------------------------------------------------------------
// QKV projection, depth-2 counted-vmcnt pipeline (T4): raw barriers, prefetch
// stays in flight across barriers (no vmcnt(0) drain in the main loop).
// z=0 -> qh; z=1 -> kc compacted scatter; z=2 -> vtc [b][h][d][rank] scatter.
// ---------------------------------------------------------------------------
__global__ __launch_bounds__(256, 2) void qkv_gemm4(
    const us* __restrict__ xbq, const us* __restrict__ xbk, const us* __restrict__ xbv,
    const us* __restrict__ wb,
    const float* __restrict__ bq, const float* __restrict__ bk, const float* __restrict__ bv,
    const float* __restrict__ zeta, const int* __restrict__ rank,
    us* __restrict__ qh, us* __restrict__ kc, us* __restrict__ vtc)
{
  const int z = blockIdx.z;
  const us* A  = (z == 0) ? xbq : (z == 1) ? xbk : xbv;
  const us* Bw = wb + (size_t)z * 589824;
  const float* bias = (z == 0) ? bq : (z == 1) ? bk : bv;

  __shared__ __align__(16) us As[2][128 * 64];
  __shared__ __align__(16) us Bs[2][128 * 64];

  const int tid = threadIdx.x, lane = tid & 63, w = tid >> 6;
  const int wr = (w >> 1) * 64, wc = (w & 1) * 64;
  const int mt = blockIdx.x, nt = blockIdx.y;

  f32x4 acc[4][4] = {};

  auto STAGE = [&](int kt, int buf){
#pragma unroll
    for (int p = 0; p < 4; ++p){
      int chunk = p * 256 + tid;
      int row = chunk >> 3, colb = (chunk & 7) * 8;
      GL16(A  + (size_t)(mt * 128 + row) * 768 + kt * 64 + colb,
           As[buf] + (p * 256 + w * 64) * 8);
      GL16(Bw + (size_t)(nt * 128 + row) * 768 + kt * 64 + colb,
           Bs[buf] + (p * 256 + w * 64) * 8);
    }
  };

  STAGE(0, 0);
  STAGE(1, 1);
  for (int kt = 0; kt < 12; ++kt){
    const int cur = kt & 1;
    // own 8 loads for tile kt arrived; tile kt+1's 8 stay in flight
    if (kt < 11) asm volatile("s_waitcnt vmcnt(8)" ::: "memory");
    else         asm volatile("s_waitcnt vmcnt(0)" ::: "memory");
    __builtin_amdgcn_s_barrier();      // all waves' kt data now in LDS

#pragma unroll
    for (int ks = 0; ks < 2; ++ks){
      short8 af[4], bf4[4];
#pragma unroll
      for (int mf = 0; mf < 4; ++mf){
        int row = wr + mf * 16 + (lane & 15);
        af[mf] = *(const short8*)(As[cur] + row * 64 + ks * 32 + (lane >> 4) * 8);
      }
#pragma unroll
      for (int nf = 0; nf < 4; ++nf){
        int row = wc + nf * 16 + (lane & 15);
        bf4[nf] = *(const short8*)(Bs[cur] + row * 64 + ks * 32 + (lane >> 4) * 8);
      }
#pragma unroll
      for (int mf = 0; mf < 4; ++mf)
#pragma unroll
        for (int nf = 0; nf < 4; ++nf)
          acc[mf][nf] = MFMA16(af[mf], bf4[nf], acc[mf][nf]);
    }

    asm volatile("s_waitcnt lgkmcnt(0)" ::: "memory");
    __builtin_amdgcn_s_barrier();      // all waves done reading buf[cur]
    if (kt < 10) STAGE(kt + 2, cur);   // overwrite now-free buffer
  }

  float bzv[4], zzv[4]; int colv[4];
#pragma unroll
  for (int nf = 0; nf < 4; ++nf){
    colv[nf] = nt * 128 + wc + nf * 16 + (lane & 15);
    bzv[nf] = bias[colv[nf]];
    zzv[nf] = zeta[colv[nf]];
  }

  if (z == 0){
#pragma unroll
    for (int mf = 0; mf < 4; ++mf)
#pragma unroll
      for (int r = 0; r < 4; ++r){
        int row = mt * 128 + wr + mf * 16 + (lane >> 4) * 4 + r;
#pragma unroll
        for (int nf = 0; nf < 4; ++nf)
          qh[(size_t)row * 768 + colv[nf]] = f2bf((acc[mf][nf][r] + bzv[nf]) * zzv[nf]);
      }
  } else {
#pragma unroll
    for (int mf = 0; mf < 4; ++mf)
#pragma unroll
      for (int r = 0; r < 4; ++r){
        int row = mt * 128 + wr + mf * 16 + (lane >> 4) * 4 + r;
        int rk = rank[row];
        if (rk < 0) continue;
        int bsel = row >> 10;
        if (z == 1){
#pragma unroll
          for (int nf = 0; nf < 4; ++nf)
            kc[(size_t)(bsel * 1024 + rk) * 768 + colv[nf]] =
                f2bf((acc[mf][nf][r] + bzv[nf]) * zzv[nf]);
        } else {
#pragma unroll
          for (int nf = 0; nf < 4; ++nf){
            int hh = colv[nf] >> 6, dd = colv[nf] & 63;
            vtc[((size_t)(bsel * 12 + hh) * 64 + dd) * 1024 + rk] =
                f2bf((acc[mf][nf][r] + bzv[nf]) * zzv[nf]);
          }
        }
      }
  }
}

// ---------------------------------------------------------------------------
// Flash attention over COMPACTED keys (~8-9 tiles vs 16).  Fixed-reference
// softmax (m == 0, exact); pad keys get p == 0 via maskc.
// ---------------------------------------------------------------------------
__global__ __launch_bounds__(256) void attn_fwd3(
    const us* __restrict__ qh, const us* __restrict__ kc,
    const us* __restrict__ vtc, const float* __restrict__ maskc,
    const int* __restrict__ nbd, us* __restrict__ ao)
{
  const int qt = blockIdx.x, h = blockIdx.y, b = blockIdx.z;
  const int tid = threadIdx.x, lane = tid & 63, w = tid >> 6;

  const int nbv = nbd[b];
  const int nt = (nbv + 63) >> 6;

  __shared__ __align__(16) us Qs[64 * 64];
  __shared__ __align__(16) us Ks[2][64 * 64];
  __shared__ __align__(16) us Vs[2][64 * 64];
  __shared__ __align__(16) us Ps[64 * 64];
  __shared__ float smask[1024];

#pragma unroll
  for (int i = 0; i < 4; ++i){
    int key = i * 256 + tid;
    smask[key] = (key < nt * 64) ? maskc[b * 1024 + key] : 0.f;
  }
#pragma unroll
  for (int p = 0; p < 2; ++p){
    int c = p * 256 + tid, row = c >> 3, db = (c & 7) * 8;
    short8 qv = *(const short8*)(qh + (size_t)(b * 1024 + qt * 64 + row) * 768 + h * 64 + db);
    *(short8*)((char*)Qs + ((row * 128 + db * 2) ^ ((row & 7) << 4))) = qv;
  }

  short8 kr[2], vr[2];
  auto KVLOAD = [&](int kt){
#pragma unroll
    for (int p = 0; p < 2; ++p){
      int c = p * 256 + tid, row = c >> 3, db = (c & 7) * 8;
      kr[p] = *(const short8*)(kc + (size_t)(b * 1024 + kt * 64 + row) * 768 + h * 64 + db);
      vr[p] = *(const short8*)(vtc + ((size_t)((b * 12 + h) * 64 + row)) * 1024 + kt * 64 + db);
    }
  };
  auto KVWRITE = [&](int buf){
#pragma unroll
    for (int p = 0; p < 2; ++p){
      int c = p * 256 + tid, row = c >> 3, db = (c & 7) * 8;
      int byte = (row * 128 + db * 2) ^ ((row & 7) << 4);
      *(short8*)((char*)Ks[buf] + byte) = kr[p];
      *(short8*)((char*)Vs[buf] + byte) = vr[p];
    }
  };
  KVLOAD(0); KVWRITE(0);
  __syncthreads();

  short8 qf[2];
#pragma unroll
  for (int ks = 0; ks < 2; ++ks){
    int row = w * 16 + (lane & 15);
    qf[ks] = *(const short8*)((const char*)Qs +
              ((row * 128 + ks * 64 + (lane >> 4) * 16) ^ ((row & 7) << 4)));
  }

  float lsum[4] = {0.f, 0.f, 0.f, 0.f};
  f32x4 o[4] = {};
  int cur = 0;
  for (int kt = 0; kt < nt; ++kt){
    if (kt + 1 < nt) KVLOAD(kt + 1);

    f32x4 s[4] = {};
#pragma unroll
    for (int ks = 0; ks < 2; ++ks)
#pragma unroll
      for (int f = 0; f < 4; ++f){
        int row = f * 16 + (lane & 15);
        short8 kf = *(const short8*)((const char*)Ks[cur] +
                    ((row * 128 + ks * 64 + (lane >> 4) * 16) ^ ((row & 7) << 4)));
        s[f] = MFMA16(qf[ks], kf, s[f]);
      }

    float mads[4];
#pragma unroll
    for (int f = 0; f < 4; ++f) mads[f] = smask[kt * 64 + f * 16 + (lane & 15)];
    float p_[4][4];
#pragma unroll
    for (int r = 0; r < 4; ++r){
#pragma unroll
      for (int f = 0; f < 4; ++f) p_[f][r] = __expf(fmaf(s[f][r], 0.125f, mads[f]));
      lsum[r] += (p_[0][r] + p_[1][r]) + (p_[2][r] + p_[3][r]);
    }

#pragma unroll
    for (int f = 0; f < 4; ++f)
#pragma unroll
      for (int r = 0; r < 4; ++r){
        int row = w * 16 + (lane >> 4) * 4 + r;
        *(us*)((char*)Ps + ((row * 128 + (f * 16 + (lane & 15)) * 2) ^ ((row & 7) << 4))) =
            f2bf(p_[f][r]);
      }

#pragma unroll
    for (int ks = 0; ks < 2; ++ks){
      int prow = w * 16 + (lane & 15);
      short8 pa = *(const short8*)((const char*)Ps +
                  ((prow * 128 + ks * 64 + (lane >> 4) * 16) ^ ((prow & 7) << 4)));
#pragma unroll
      for (int df = 0; df < 4; ++df){
        int vrow = df * 16 + (lane & 15);
        short8 vb = *(const short8*)((const char*)Vs[cur] +
                    ((vrow * 128 + ks * 64 + (lane >> 4) * 16) ^ ((vrow & 7) << 4)));
        o[df] = MFMA16(pa, vb, o[df]);
      }
    }

    if (kt + 1 < nt) KVWRITE(cur ^ 1);
    __syncthreads();
    cur ^= 1;
  }

  float linv[4];
#pragma unroll
  for (int r = 0; r < 4; ++r){
    float l = lsum[r];
    l += __shfl_xor(l, 1, 64); l += __shfl_xor(l, 2, 64);
    l += __shfl_xor(l, 4, 64); l += __shfl_xor(l, 8, 64);
    linv[r] = __builtin_amdgcn_rcpf(l);
  }
#pragma unroll
  for (int df = 0; df < 4; ++df)
#pragma unroll
    for (int r = 0; r < 4; ++r){
      int qrow = qt * 64 + w * 16 + (lane >> 4) * 4 + r;
      int dcol = df * 16 + (lane & 15);
      ao[(size_t)(b * 1024 + qrow) * 768 + h * 64 + dcol] = f2bf(o[df][r] * linv[r]);
    }
}

// ---------------------------------------------------------------------------
// Output projection, depth-2 counted-vmcnt pipeline; fp32 out to [n][b][c].
// ---------------------------------------------------------------------------
__global__ __launch_bounds__(256, 2) void out_gemm3(
    const us* __restrict__ ain, const us* __restrict__ wo,
    const float* __restrict__ bo, float* __restrict__ dout)
{
  __shared__ __align__(16) us As[2][128 * 64];
  __shared__ __align__(16) us Bs[2][128 * 64];

  const int tid = threadIdx.x, lane = tid & 63, w = tid >> 6;
  const int wr = (w >> 1) * 64, wc = (w & 1) * 64;
  const int mt = blockIdx.x, nt = blockIdx.y;

  f32x4 acc[4][4] = {};

  auto STAGE = [&](int kt, int buf){
#pragma unroll
    for (int p = 0; p < 4; ++p){
      int chunk = p * 256 + tid;
      int row = chunk >> 3, colb = (chunk & 7) * 8;
      GL16(ain + (size_t)(mt * 128 + row) * 768 + kt * 64 + colb,
           As[buf] + (p * 256 + w * 64) * 8);
      GL16(wo  + (size_t)(nt * 128 + row) * 768 + kt * 64 + colb,
           Bs[buf] + (p * 256 + w * 64) * 8);
    }
  };

  STAGE(0, 0);
  STAGE(1, 1);
  for (int kt = 0; kt < 12; ++kt){
    const int cur = kt & 1;
    if (kt < 11) asm volatile("s_waitcnt vmcnt(8)" ::: "memory");
    else         asm volatile("s_waitcnt vmcnt(0)" ::: "memory");
    __builtin_amdgcn_s_barrier();

#pragma unroll
    for (int ks = 0; ks < 2; ++ks){
      short8 af[4], bf4[4];
#pragma unroll
      for (int mf = 0; mf < 4; ++mf){
        int row = wr + mf * 16 + (lane & 15);
        af[mf] = *(const short8*)(As[cur] + row * 64 + ks * 32 + (lane >> 4) * 8);
      }
#pragma unroll
      for (int nf = 0; nf < 4; ++nf){
        int row = wc + nf * 16 + (lane & 15);
        bf4[nf] = *(const short8*)(Bs[cur] + row * 64 + ks * 32 + (lane >> 4) * 8);
      }
#pragma unroll
      for (int mf = 0; mf < 4; ++mf)
#pragma unroll
        for (int nf = 0; nf < 4; ++nf)
          acc[mf][nf] = MFMA16(af[mf], bf4[nf], acc[mf][nf]);
    }

    asm volatile("s_waitcnt lgkmcnt(0)" ::: "memory");
    __builtin_amdgcn_s_barrier();
    if (kt < 10) STAGE(kt + 2, cur);
  }

#pragma unroll
  for (int nf = 0; nf < 4; ++nf){
    int col = nt * 128 + wc + nf * 16 + (lane & 15);
    float bz = bo[col];
#pragma unroll
    for (int mf = 0; mf < 4; ++mf)
#pragma unroll
      for (int r = 0; r < 4; ++r){
        int row = mt * 128 + wr + mf * 16 + (lane >> 4) * 4 + r;
        int n = row & 1023, bsel = row >> 10;
        dout[(size_t)(n * 4 + bsel) * 768 + col] = acc[mf][nf][r] + bz;
      }
  }
}

extern "C" void kernel_launch(void* const* d_in, const int* in_sizes, int n_in,
                              void* d_out, int out_size, void* d_ws, size_t ws_size,
                              hipStream_t stream)
{
  const float* q    = (const float*)d_in[0];
  const float* k    = (const float*)d_in[1];
  const float* v    = (const float*)d_in[2];
  const int*   mask = (const int*)d_in[3];
  const float* Wq   = (const float*)d_in[4];
  const float* bq   = (const float*)d_in[5];
  const float* Wk   = (const float*)d_in[6];
  const float* bk   = (const float*)d_in[7];
  const float* Wv   = (const float*)d_in[8];
  const float* bv   = (const float*)d_in[9];
  const float* Wo   = (const float*)d_in[10];
  const float* bo   = (const float*)d_in[11];
  const float* zeta = (const float*)d_in[12];

  // bf16 x for q/k parked inside d_out (overwritten by final GEMM)
  us* xbq = (us*)d_out;
  us* xbk = xbq + 3145728;
  // workspace layout (≈29.9 MB total)
  us* xbv = (us*)d_ws;
  us* wb  = xbv + 3145728;      // 4 x 768 x 768 bf16 weights
  us* qh  = wb  + 2359296;
  us* kc  = qh  + 3145728;      // compacted K rows [b*1024 + rank][768]
  us* vtc = kc  + 3145728;      // compacted V^T [b][h][d][rank]
  int*   rank  = (int*)(vtc + 3145728);
  int*   nbd   = rank + 4096;
  float* maskc = (float*)(nbd + 4);
  us* ao = xbv;                 // reuse: xbv dead after qkv_gemm4

  convert_all<<<5760, 256, 0, stream>>>(q, k, v, Wq, Wk, Wv, Wo, xbq, xbk, xbv, wb);
  compact_idx<<<4, 256, 0, stream>>>(mask, rank, nbd, maskc);
  hipMemsetAsync(kc,  0, (size_t)4096 * 768 * 2, stream);   // pad rows read as 0
  hipMemsetAsync(vtc, 0, (size_t)4096 * 768 * 2, stream);   // pad cols read as 0
  qkv_gemm4<<<dim3(32, 6, 3), 256, 0, stream>>>(xbq, xbk, xbv, wb, bq, bk, bv,
                                                zeta, rank, qh, kc, vtc);
  attn_fwd3<<<dim3(16, 12, 4), 256, 0, stream>>>(qh, kc, vtc, maskc, nbd, ao);
  out_gemm3<<<dim3(32, 6, 1), 256, 0, stream>>>(ao, wb + 3 * 589824, bo, (float*)d_out);
}

// Round 5
// 83.669 us; speedup vs baseline: 1.3035x; 1.1134x over previous
//
#include <hip/hip_runtime.h>
#include <cstdint>
#include <cstddef>

typedef unsigned short us;
using short8 = __attribute__((ext_vector_type(8))) short;  // 8 bf16
using f32x4  = __attribute__((ext_vector_type(4))) float;

union U8 { us u[8]; short8 v; };

#define MFMA16(a,b,c) __builtin_amdgcn_mfma_f32_16x16x32_bf16((a),(b),(c),0,0,0)

static __device__ __forceinline__ us f2bf(float f){
  union { float f; unsigned u; } cv; cv.f = f;
  unsigned u = cv.u;
  return (us)((u + 0x7fffu + ((u >> 16) & 1u)) >> 16);
}

typedef const __attribute__((address_space(1))) void* gp_t;
typedef __attribute__((address_space(3))) void* lp_t;
#define GL16(g,l) __builtin_amdgcn_global_load_lds((gp_t)(g),(lp_t)(l),16,0,0)

// ---------------------------------------------------------------------------
// Convert fp32 inputs to bf16.  x tensors reordered [n][b][c] -> [b*1024+n][c].
// ---------------------------------------------------------------------------
__global__ __launch_bounds__(256) void convert_all(
    const float* __restrict__ xq, const float* __restrict__ xk, const float* __restrict__ xv,
    const float* __restrict__ Wq, const float* __restrict__ Wk,
    const float* __restrict__ Wv, const float* __restrict__ Wo,
    us* __restrict__ xbq, us* __restrict__ xbk, us* __restrict__ xbv,
    us* __restrict__ wb)
{
  unsigned id = blockIdx.x * 256u + threadIdx.x;
  const float* src; us* dst;
  if (id < 1179648u){                      // 3 * 4096 * 96
    unsigned z  = id / 393216u;
    unsigned rr = id - z * 393216u;
    unsigned row = rr / 96u, cc = rr - row * 96u;
    unsigned bsel = row >> 10, n = row & 1023u;
    const float* x = (z == 0) ? xq : (z == 1) ? xk : xv;
    us* xb = (z == 0) ? xbq : (z == 1) ? xbk : xbv;
    src = x  + (size_t)(n * 4u + bsel) * 768u + cc * 8u;
    dst = xb + (size_t)row * 768u + cc * 8u;
  } else {                                 // 4 * 73728 W chunks
    unsigned wi = id - 1179648u;
    unsigned z  = wi / 73728u;
    unsigned rr = wi - z * 73728u;
    const float* W = (z == 0) ? Wq : (z == 1) ? Wk : (z == 2) ? Wv : Wo;
    src = W  + (size_t)rr * 8u;
    dst = wb + (size_t)z * 589824u + rr * 8u;
  }
  f32x4 a = *(const f32x4*)src;
  f32x4 b = *(const f32x4*)(src + 4);
  U8 o;
#pragma unroll
  for (int j = 0; j < 4; ++j){ o.u[j] = f2bf(a[j]); o.u[4 + j] = f2bf(b[j]); }
  *(short8*)dst = o.v;
}

// ---------------------------------------------------------------------------
// Zero the kc+vtc region (12.58 MB, exact cover: 3072 blocks x 256 x 16B).
// ---------------------------------------------------------------------------
__global__ __launch_bounds__(256) void zero_ws(f32x4* __restrict__ p)
{
  p[(size_t)blockIdx.x * 256 + threadIdx.x] = f32x4{};
}

// ---------------------------------------------------------------------------
// Mask compaction (index/mask tables only).
// ---------------------------------------------------------------------------
__global__ __launch_bounds__(256) void compact_idx(
    const int* __restrict__ mask, int* __restrict__ rank, int* __restrict__ nbd,
    float* __restrict__ maskc)
{
  const int b = blockIdx.x, tid = threadIdx.x, lane = tid & 63, w = tid >> 6;
  __shared__ int wsum[4];

  int m[4], cnt = 0;
#pragma unroll
  for (int j = 0; j < 4; ++j){
    m[j] = mask[b * 1024 + tid * 4 + j] ? 0 : 1;
    cnt += m[j];
  }
  int sc = cnt;
#pragma unroll
  for (int off = 1; off < 64; off <<= 1){
    int t = __shfl_up(sc, off, 64);
    if (lane >= off) sc += t;
  }
  if (lane == 63) wsum[w] = sc;
  __syncthreads();
  int woff = 0;
#pragma unroll
  for (int i = 0; i < 4; ++i) if (i < w) woff += wsum[i];
  const int total = wsum[0] + wsum[1] + wsum[2] + wsum[3];
  int rr = woff + sc - cnt;
#pragma unroll
  for (int j = 0; j < 4; ++j){
    rank[b * 1024 + tid * 4 + j] = m[j] ? rr : -1;
    rr += m[j];
  }
  if (tid == 0) nbd[b] = total;

  const int ceil64 = (total + 63) & ~63;
  for (int j = tid; j < ceil64; j += 256)
    maskc[b * 1024 + j] = (j < total) ? 0.f : -1.25e29f;
}

// ---------------------------------------------------------------------------
// QKV projection: depth-2 counted-vmcnt pipeline + T2 swizzle (source-side
// pre-swizzled global addr, linear gload_lds dest, XOR'd ds_read) + XCD remap.
// ---------------------------------------------------------------------------
__global__ __launch_bounds__(256, 2) void qkv_gemm5(
    const us* __restrict__ xbq, const us* __restrict__ xbk, const us* __restrict__ xbv,
    const us* __restrict__ wb,
    const float* __restrict__ bq, const float* __restrict__ bk, const float* __restrict__ bv,
    const float* __restrict__ zeta, const int* __restrict__ rank,
    us* __restrict__ qh, us* __restrict__ kc, us* __restrict__ vtc)
{
  const int z = blockIdx.z;
  const us* A  = (z == 0) ? xbq : (z == 1) ? xbk : xbv;
  const us* Bw = wb + (size_t)z * 589824;
  const float* bias = (z == 0) ? bq : (z == 1) ? bk : bv;

  __shared__ __align__(16) us As[2][128 * 64];
  __shared__ __align__(16) us Bs[2][128 * 64];

  const int tid = threadIdx.x, lane = tid & 63, w = tid >> 6;
  const int wr = (w >> 1) * 64, wc = (w & 1) * 64;
  // XCD-contiguous remap: each XCD owns 4 consecutive mt x all 6 nt
  // (~2 MB working set -> fits its 4 MB L2).  Bijective on 192 blocks/z.
  const int flat = blockIdx.x + blockIdx.y * 32;
  const int xcd = flat & 7, c = flat >> 3;
  const int mt = xcd * 4 + (c & 3);
  const int nt = c >> 2;

  f32x4 acc[4][4] = {};

  auto STAGE = [&](int kt, int buf){
#pragma unroll
    for (int p = 0; p < 4; ++p){
      int chunk = p * 256 + tid;
      int row = chunk >> 3;
      int colb = ((chunk & 7) ^ (row & 7)) * 8;      // pre-swizzled source col
      GL16(A  + (size_t)(mt * 128 + row) * 768 + kt * 64 + colb,
           As[buf] + (p * 256 + w * 64) * 8);
      GL16(Bw + (size_t)(nt * 128 + row) * 768 + kt * 64 + colb,
           Bs[buf] + (p * 256 + w * 64) * 8);
    }
  };

  STAGE(0, 0);
  STAGE(1, 1);
  for (int kt = 0; kt < 12; ++kt){
    const int cur = kt & 1;
    if (kt < 11) asm volatile("s_waitcnt vmcnt(8)" ::: "memory");
    else         asm volatile("s_waitcnt vmcnt(0)" ::: "memory");
    __builtin_amdgcn_s_barrier();

#pragma unroll
    for (int ks = 0; ks < 2; ++ks){
      short8 af[4], bf4[4];
#pragma unroll
      for (int mf = 0; mf < 4; ++mf){
        int row = wr + mf * 16 + (lane & 15);
        int byte = (row * 128 + ks * 64 + (lane >> 4) * 16) ^ ((row & 7) << 4);
        af[mf] = *(const short8*)((const char*)As[cur] + byte);
      }
#pragma unroll
      for (int nf = 0; nf < 4; ++nf){
        int row = wc + nf * 16 + (lane & 15);
        int byte = (row * 128 + ks * 64 + (lane >> 4) * 16) ^ ((row & 7) << 4);
        bf4[nf] = *(const short8*)((const char*)Bs[cur] + byte);
      }
#pragma unroll
      for (int mf = 0; mf < 4; ++mf)
#pragma unroll
        for (int nf = 0; nf < 4; ++nf)
          acc[mf][nf] = MFMA16(af[mf], bf4[nf], acc[mf][nf]);
    }

    asm volatile("s_waitcnt lgkmcnt(0)" ::: "memory");
    __builtin_amdgcn_s_barrier();
    if (kt < 10) STAGE(kt + 2, cur);
  }

  float bzv[4], zzv[4]; int colv[4];
#pragma unroll
  for (int nf = 0; nf < 4; ++nf){
    colv[nf] = nt * 128 + wc + nf * 16 + (lane & 15);
    bzv[nf] = bias[colv[nf]];
    zzv[nf] = zeta[colv[nf]];
  }

  if (z == 0){
#pragma unroll
    for (int mf = 0; mf < 4; ++mf)
#pragma unroll
      for (int r = 0; r < 4; ++r){
        int row = mt * 128 + wr + mf * 16 + (lane >> 4) * 4 + r;
#pragma unroll
        for (int nf = 0; nf < 4; ++nf)
          qh[(size_t)row * 768 + colv[nf]] = f2bf((acc[mf][nf][r] + bzv[nf]) * zzv[nf]);
      }
  } else {
#pragma unroll
    for (int mf = 0; mf < 4; ++mf)
#pragma unroll
      for (int r = 0; r < 4; ++r){
        int row = mt * 128 + wr + mf * 16 + (lane >> 4) * 4 + r;
        int rk = rank[row];
        if (rk < 0) continue;
        int bsel = row >> 10;
        if (z == 1){
#pragma unroll
          for (int nf = 0; nf < 4; ++nf)
            kc[(size_t)(bsel * 1024 + rk) * 768 + colv[nf]] =
                f2bf((acc[mf][nf][r] + bzv[nf]) * zzv[nf]);
        } else {
#pragma unroll
          for (int nf = 0; nf < 4; ++nf){
            int hh = colv[nf] >> 6, dd = colv[nf] & 63;
            vtc[((size_t)(bsel * 12 + hh) * 64 + dd) * 1024 + rk] =
                f2bf((acc[mf][nf][r] + bzv[nf]) * zzv[nf]);
          }
        }
      }
  }
}

// ---------------------------------------------------------------------------
// Flash attention over COMPACTED keys.  Fixed-reference softmax (m == 0).
// XCD remap: 6 (b,h) pairs per XCD so all 16 qt blocks hit K/V in own L2.
// ---------------------------------------------------------------------------
__global__ __launch_bounds__(256) void attn_fwd4(
    const us* __restrict__ qh, const us* __restrict__ kc,
    const us* __restrict__ vtc, const float* __restrict__ maskc,
    const int* __restrict__ nbd, us* __restrict__ ao)
{
  const int flat = blockIdx.x + 16 * blockIdx.y + 192 * blockIdx.z;
  const int xcd = flat & 7, c = flat >> 3;          // c in [0,96)
  const int pair = xcd * 6 + (c >> 4);              // [0,48)
  const int qt = c & 15, h = pair % 12, b = pair / 12;
  const int tid = threadIdx.x, lane = tid & 63, w = tid >> 6;

  const int nbv = nbd[b];
  const int nt = (nbv + 63) >> 6;

  __shared__ __align__(16) us Qs[64 * 64];
  __shared__ __align__(16) us Ks[2][64 * 64];
  __shared__ __align__(16) us Vs[2][64 * 64];
  __shared__ __align__(16) us Ps[64 * 64];
  __shared__ float smask[1024];

#pragma unroll
  for (int i = 0; i < 4; ++i){
    int key = i * 256 + tid;
    smask[key] = (key < nt * 64) ? maskc[b * 1024 + key] : 0.f;
  }
#pragma unroll
  for (int p = 0; p < 2; ++p){
    int cc = p * 256 + tid, row = cc >> 3, db = (cc & 7) * 8;
    short8 qv = *(const short8*)(qh + (size_t)(b * 1024 + qt * 64 + row) * 768 + h * 64 + db);
    *(short8*)((char*)Qs + ((row * 128 + db * 2) ^ ((row & 7) << 4))) = qv;
  }

  short8 kr[2], vr[2];
  auto KVLOAD = [&](int kt){
#pragma unroll
    for (int p = 0; p < 2; ++p){
      int cc = p * 256 + tid, row = cc >> 3, db = (cc & 7) * 8;
      kr[p] = *(const short8*)(kc + (size_t)(b * 1024 + kt * 64 + row) * 768 + h * 64 + db);
      vr[p] = *(const short8*)(vtc + ((size_t)((b * 12 + h) * 64 + row)) * 1024 + kt * 64 + db);
    }
  };
  auto KVWRITE = [&](int buf){
#pragma unroll
    for (int p = 0; p < 2; ++p){
      int cc = p * 256 + tid, row = cc >> 3, db = (cc & 7) * 8;
      int byte = (row * 128 + db * 2) ^ ((row & 7) << 4);
      *(short8*)((char*)Ks[buf] + byte) = kr[p];
      *(short8*)((char*)Vs[buf] + byte) = vr[p];
    }
  };
  KVLOAD(0); KVWRITE(0);
  __syncthreads();

  short8 qf[2];
#pragma unroll
  for (int ks = 0; ks < 2; ++ks){
    int row = w * 16 + (lane & 15);
    qf[ks] = *(const short8*)((const char*)Qs +
              ((row * 128 + ks * 64 + (lane >> 4) * 16) ^ ((row & 7) << 4)));
  }

  float lsum[4] = {0.f, 0.f, 0.f, 0.f};
  f32x4 o[4] = {};
  int cur = 0;
  for (int kt = 0; kt < nt; ++kt){
    if (kt + 1 < nt) KVLOAD(kt + 1);

    f32x4 s[4] = {};
#pragma unroll
    for (int ks = 0; ks < 2; ++ks)
#pragma unroll
      for (int f = 0; f < 4; ++f){
        int row = f * 16 + (lane & 15);
        short8 kf = *(const short8*)((const char*)Ks[cur] +
                    ((row * 128 + ks * 64 + (lane >> 4) * 16) ^ ((row & 7) << 4)));
        s[f] = MFMA16(qf[ks], kf, s[f]);
      }

    float mads[4];
#pragma unroll
    for (int f = 0; f < 4; ++f) mads[f] = smask[kt * 64 + f * 16 + (lane & 15)];
    float p_[4][4];
#pragma unroll
    for (int r = 0; r < 4; ++r){
#pragma unroll
      for (int f = 0; f < 4; ++f) p_[f][r] = __expf(fmaf(s[f][r], 0.125f, mads[f]));
      lsum[r] += (p_[0][r] + p_[1][r]) + (p_[2][r] + p_[3][r]);
    }

#pragma unroll
    for (int f = 0; f < 4; ++f)
#pragma unroll
      for (int r = 0; r < 4; ++r){
        int row = w * 16 + (lane >> 4) * 4 + r;
        *(us*)((char*)Ps + ((row * 128 + (f * 16 + (lane & 15)) * 2) ^ ((row & 7) << 4))) =
            f2bf(p_[f][r]);
      }

#pragma unroll
    for (int ks = 0; ks < 2; ++ks){
      int prow = w * 16 + (lane & 15);
      short8 pa = *(const short8*)((const char*)Ps +
                  ((prow * 128 + ks * 64 + (lane >> 4) * 16) ^ ((prow & 7) << 4)));
#pragma unroll
      for (int df = 0; df < 4; ++df){
        int vrow = df * 16 + (lane & 15);
        short8 vb = *(const short8*)((const char*)Vs[cur] +
                    ((vrow * 128 + ks * 64 + (lane >> 4) * 16) ^ ((vrow & 7) << 4)));
        o[df] = MFMA16(pa, vb, o[df]);
      }
    }

    if (kt + 1 < nt) KVWRITE(cur ^ 1);
    __syncthreads();
    cur ^= 1;
  }

  float linv[4];
#pragma unroll
  for (int r = 0; r < 4; ++r){
    float l = lsum[r];
    l += __shfl_xor(l, 1, 64); l += __shfl_xor(l, 2, 64);
    l += __shfl_xor(l, 4, 64); l += __shfl_xor(l, 8, 64);
    linv[r] = __builtin_amdgcn_rcpf(l);
  }
#pragma unroll
  for (int df = 0; df < 4; ++df)
#pragma unroll
    for (int r = 0; r < 4; ++r){
      int qrow = qt * 64 + w * 16 + (lane >> 4) * 4 + r;
      int dcol = df * 16 + (lane & 15);
      ao[(size_t)(b * 1024 + qrow) * 768 + h * 64 + dcol] = f2bf(o[df][r] * linv[r]);
    }
}

// ---------------------------------------------------------------------------
// Output projection: same pipeline + swizzle + remap; fp32 out to [n][b][c].
// ---------------------------------------------------------------------------
__global__ __launch_bounds__(256, 2) void out_gemm4(
    const us* __restrict__ ain, const us* __restrict__ wo,
    const float* __restrict__ bo, float* __restrict__ dout)
{
  __shared__ __align__(16) us As[2][128 * 64];
  __shared__ __align__(16) us Bs[2][128 * 64];

  const int tid = threadIdx.x, lane = tid & 63, w = tid >> 6;
  const int wr = (w >> 1) * 64, wc = (w & 1) * 64;
  const int flat = blockIdx.x + blockIdx.y * 32;
  const int xcd = flat & 7, c = flat >> 3;
  const int mt = xcd * 4 + (c & 3);
  const int nt = c >> 2;

  f32x4 acc[4][4] = {};

  auto STAGE = [&](int kt, int buf){
#pragma unroll
    for (int p = 0; p < 4; ++p){
      int chunk = p * 256 + tid;
      int row = chunk >> 3;
      int colb = ((chunk & 7) ^ (row & 7)) * 8;
      GL16(ain + (size_t)(mt * 128 + row) * 768 + kt * 64 + colb,
           As[buf] + (p * 256 + w * 64) * 8);
      GL16(wo  + (size_t)(nt * 128 + row) * 768 + kt * 64 + colb,
           Bs[buf] + (p * 256 + w * 64) * 8);
    }
  };

  STAGE(0, 0);
  STAGE(1, 1);
  for (int kt = 0; kt < 12; ++kt){
    const int cur = kt & 1;
    if (kt < 11) asm volatile("s_waitcnt vmcnt(8)" ::: "memory");
    else         asm volatile("s_waitcnt vmcnt(0)" ::: "memory");
    __builtin_amdgcn_s_barrier();

#pragma unroll
    for (int ks = 0; ks < 2; ++ks){
      short8 af[4], bf4[4];
#pragma unroll
      for (int mf = 0; mf < 4; ++mf){
        int row = wr + mf * 16 + (lane & 15);
        int byte = (row * 128 + ks * 64 + (lane >> 4) * 16) ^ ((row & 7) << 4);
        af[mf] = *(const short8*)((const char*)As[cur] + byte);
      }
#pragma unroll
      for (int nf = 0; nf < 4; ++nf){
        int row = wc + nf * 16 + (lane & 15);
        int byte = (row * 128 + ks * 64 + (lane >> 4) * 16) ^ ((row & 7) << 4);
        bf4[nf] = *(const short8*)((const char*)Bs[cur] + byte);
      }
#pragma unroll
      for (int mf = 0; mf < 4; ++mf)
#pragma unroll
        for (int nf = 0; nf < 4; ++nf)
          acc[mf][nf] = MFMA16(af[mf], bf4[nf], acc[mf][nf]);
    }

    asm volatile("s_waitcnt lgkmcnt(0)" ::: "memory");
    __builtin_amdgcn_s_barrier();
    if (kt < 10) STAGE(kt + 2, cur);
  }

#pragma unroll
  for (int nf = 0; nf < 4; ++nf){
    int col = nt * 128 + wc + nf * 16 + (lane & 15);
    float bz = bo[col];
#pragma unroll
    for (int mf = 0; mf < 4; ++mf)
#pragma unroll
      for (int r = 0; r < 4; ++r){
        int row = mt * 128 + wr + mf * 16 + (lane >> 4) * 4 + r;
        int n = row & 1023, bsel = row >> 10;
        dout[(size_t)(n * 4 + bsel) * 768 + col] = acc[mf][nf][r] + bz;
      }
  }
}

extern "C" void kernel_launch(void* const* d_in, const int* in_sizes, int n_in,
                              void* d_out, int out_size, void* d_ws, size_t ws_size,
                              hipStream_t stream)
{
  const float* q    = (const float*)d_in[0];
  const float* k    = (const float*)d_in[1];
  const float* v    = (const float*)d_in[2];
  const int*   mask = (const int*)d_in[3];
  const float* Wq   = (const float*)d_in[4];
  const float* bq   = (const float*)d_in[5];
  const float* Wk   = (const float*)d_in[6];
  const float* bk   = (const float*)d_in[7];
  const float* Wv   = (const float*)d_in[8];
  const float* bv   = (const float*)d_in[9];
  const float* Wo   = (const float*)d_in[10];
  const float* bo   = (const float*)d_in[11];
  const float* zeta = (const float*)d_in[12];

  // bf16 x for q/k parked inside d_out (overwritten by final GEMM)
  us* xbq = (us*)d_out;
  us* xbk = xbq + 3145728;
  // workspace layout
  us* xbv = (us*)d_ws;
  us* wb  = xbv + 3145728;      // 4 x 768 x 768 bf16 weights
  us* qh  = wb  + 2359296;
  us* kc  = qh  + 3145728;      // compacted K rows [b*1024 + rank][768]
  us* vtc = kc  + 3145728;      // compacted V^T [b][h][d][rank]
  int*   rank  = (int*)(vtc + 3145728);
  int*   nbd   = rank + 4096;
  float* maskc = (float*)(nbd + 4);
  us* ao = xbv;                 // reuse: xbv dead after qkv_gemm5

  convert_all<<<5760, 256, 0, stream>>>(q, k, v, Wq, Wk, Wv, Wo, xbq, xbk, xbv, wb);
  compact_idx<<<4, 256, 0, stream>>>(mask, rank, nbd, maskc);
  zero_ws<<<3072, 256, 0, stream>>>((f32x4*)kc);   // zero kc+vtc (12.58 MB exact)
  qkv_gemm5<<<dim3(32, 6, 3), 256, 0, stream>>>(xbq, xbk, xbv, wb, bq, bk, bv,
                                                zeta, rank, qh, kc, vtc);
  attn_fwd4<<<dim3(16, 12, 4), 256, 0, stream>>>(qh, kc, vtc, maskc, nbd, ao);
  out_gemm4<<<dim3(32, 6, 1), 256, 0, stream>>>(ao, wb + 3 * 589824, bo, (float*)d_out);
}

// Round 8
// 80.487 us; speedup vs baseline: 1.3551x; 1.0395x over previous
//
#include <hip/hip_runtime.h>
#include <cstdint>
#include <cstddef>

typedef unsigned short us;
using short8 = __attribute__((ext_vector_type(8))) short;  // 8 bf16
using f32x4  = __attribute__((ext_vector_type(4))) float;

union U8 { us u[8]; short8 v; };
union PU { int w[4]; short8 v; };

#define MFMA16(a,b,c) __builtin_amdgcn_mfma_f32_16x16x32_bf16((a),(b),(c),0,0,0)

static __device__ __forceinline__ us f2bf(float f){
  union { float f; unsigned u; } cv; cv.f = f;
  unsigned u = cv.u;
  return (us)((u + 0x7fffu + ((u >> 16) & 1u)) >> 16);
}

typedef const __attribute__((address_space(1))) void* gp_t;
typedef __attribute__((address_space(3))) void* lp_t;
#define GL16(g,l) __builtin_amdgcn_global_load_lds((gp_t)(g),(lp_t)(l),16,0,0)

// ---------------------------------------------------------------------------
// prep: fused {fp32->bf16 convert | zero kc/vtc pad region | mask compaction}.
// ---------------------------------------------------------------------------
__global__ __launch_bounds__(256) void prep(
    const float* __restrict__ xq, const float* __restrict__ xk, const float* __restrict__ xv,
    const float* __restrict__ Wq, const float* __restrict__ Wk,
    const float* __restrict__ Wv, const float* __restrict__ Wo,
    const int* __restrict__ mask,
    us* __restrict__ xbq, us* __restrict__ xbk, us* __restrict__ xbv,
    us* __restrict__ wb, f32x4* __restrict__ zreg,
    int* __restrict__ rank, int* __restrict__ nbd)
{
  const int bid = blockIdx.x, tid = threadIdx.x;
  if (bid < 5760){
    unsigned id = bid * 256u + tid;
    const float* src; us* dst;
    if (id < 1179648u){                      // 3 * 4096 * 96
      unsigned z  = id / 393216u;
      unsigned rr = id - z * 393216u;
      unsigned row = rr / 96u, cc = rr - row * 96u;
      unsigned bsel = row >> 10, n = row & 1023u;
      const float* x = (z == 0) ? xq : (z == 1) ? xk : xv;
      us* xb = (z == 0) ? xbq : (z == 1) ? xbk : xbv;
      src = x  + (size_t)(n * 4u + bsel) * 768u + cc * 8u;
      dst = xb + (size_t)row * 768u + cc * 8u;
    } else {                                 // 4 * 73728 W chunks
      unsigned wi = id - 1179648u;
      unsigned z  = wi / 73728u;
      unsigned rr = wi - z * 73728u;
      const float* W = (z == 0) ? Wq : (z == 1) ? Wk : (z == 2) ? Wv : Wo;
      src = W  + (size_t)rr * 8u;
      dst = wb + (size_t)z * 589824u + rr * 8u;
    }
    f32x4 a = *(const f32x4*)src;
    f32x4 b = *(const f32x4*)(src + 4);
    U8 o;
#pragma unroll
    for (int j = 0; j < 4; ++j){ o.u[j] = f2bf(a[j]); o.u[4 + j] = f2bf(b[j]); }
    *(short8*)dst = o.v;
  } else if (bid < 8832){
    zreg[(size_t)(bid - 5760) * 256 + tid] = f32x4{};
  } else {
    const int b = bid - 8832, lane = tid & 63, w = tid >> 6;
    __shared__ int wsum[4];
    int m[4], cnt = 0;
#pragma unroll
    for (int j = 0; j < 4; ++j){
      m[j] = mask[b * 1024 + tid * 4 + j] ? 0 : 1;
      cnt += m[j];
    }
    int sc = cnt;
#pragma unroll
    for (int off = 1; off < 64; off <<= 1){
      int t = __shfl_up(sc, off, 64);
      if (lane >= off) sc += t;
    }
    if (lane == 63) wsum[w] = sc;
    __syncthreads();
    int woff = 0;
#pragma unroll
    for (int i = 0; i < 4; ++i) if (i < w) woff += wsum[i];
    const int total = wsum[0] + wsum[1] + wsum[2] + wsum[3];
    int rr = woff + sc - cnt;
#pragma unroll
    for (int j = 0; j < 4; ++j){
      rank[b * 1024 + tid * 4 + j] = m[j] ? rr : -1;
      rr += m[j];
    }
    if (tid == 0) nbd[b] = total;
  }
}

// ---------------------------------------------------------------------------
// QKV projection: depth-2 counted-vmcnt pipeline + T2 swizzle + XCD remap.
// ---------------------------------------------------------------------------
__global__ __launch_bounds__(256, 2) void qkv_gemm5(
    const us* __restrict__ xbq, const us* __restrict__ xbk, const us* __restrict__ xbv,
    const us* __restrict__ wb,
    const float* __restrict__ bq, const float* __restrict__ bk, const float* __restrict__ bv,
    const float* __restrict__ zeta, const int* __restrict__ rank,
    us* __restrict__ qh, us* __restrict__ kc, us* __restrict__ vtc)
{
  const int z = blockIdx.z;
  const us* A  = (z == 0) ? xbq : (z == 1) ? xbk : xbv;
  const us* Bw = wb + (size_t)z * 589824;
  const float* bias = (z == 0) ? bq : (z == 1) ? bk : bv;

  __shared__ __align__(16) us As[2][128 * 64];
  __shared__ __align__(16) us Bs[2][128 * 64];

  const int tid = threadIdx.x, lane = tid & 63, w = tid >> 6;
  const int wr = (w >> 1) * 64, wc = (w & 1) * 64;
  const int flat = blockIdx.x + blockIdx.y * 32;
  const int xcd = flat & 7, c = flat >> 3;
  const int mt = xcd * 4 + (c & 3);
  const int nt = c >> 2;

  f32x4 acc[4][4] = {};

  auto STAGE = [&](int kt, int buf){
#pragma unroll
    for (int p = 0; p < 4; ++p){
      int chunk = p * 256 + tid;
      int row = chunk >> 3;
      int colb = ((chunk & 7) ^ (row & 7)) * 8;      // pre-swizzled source col
      GL16(A  + (size_t)(mt * 128 + row) * 768 + kt * 64 + colb,
           As[buf] + (p * 256 + w * 64) * 8);
      GL16(Bw + (size_t)(nt * 128 + row) * 768 + kt * 64 + colb,
           Bs[buf] + (p * 256 + w * 64) * 8);
    }
  };

  STAGE(0, 0);
  STAGE(1, 1);
  for (int kt = 0; kt < 12; ++kt){
    const int cur = kt & 1;
    if (kt < 11) asm volatile("s_waitcnt vmcnt(8)" ::: "memory");
    else         asm volatile("s_waitcnt vmcnt(0)" ::: "memory");
    __builtin_amdgcn_s_barrier();

#pragma unroll
    for (int ks = 0; ks < 2; ++ks){
      short8 af[4], bf4[4];
#pragma unroll
      for (int mf = 0; mf < 4; ++mf){
        int row = wr + mf * 16 + (lane & 15);
        int byte = (row * 128 + ks * 64 + (lane >> 4) * 16) ^ ((row & 7) << 4);
        af[mf] = *(const short8*)((const char*)As[cur] + byte);
      }
#pragma unroll
      for (int nf = 0; nf < 4; ++nf){
        int row = wc + nf * 16 + (lane & 15);
        int byte = (row * 128 + ks * 64 + (lane >> 4) * 16) ^ ((row & 7) << 4);
        bf4[nf] = *(const short8*)((const char*)Bs[cur] + byte);
      }
#pragma unroll
      for (int mf = 0; mf < 4; ++mf)
#pragma unroll
        for (int nf = 0; nf < 4; ++nf)
          acc[mf][nf] = MFMA16(af[mf], bf4[nf], acc[mf][nf]);
    }

    asm volatile("s_waitcnt lgkmcnt(0)" ::: "memory");
    __builtin_amdgcn_s_barrier();
    if (kt < 10) STAGE(kt + 2, cur);
  }

  float bzv[4], zzv[4]; int colv[4];
#pragma unroll
  for (int nf = 0; nf < 4; ++nf){
    colv[nf] = nt * 128 + wc + nf * 16 + (lane & 15);
    bzv[nf] = bias[colv[nf]];
    zzv[nf] = zeta[colv[nf]];
  }

  if (z == 0){
#pragma unroll
    for (int mf = 0; mf < 4; ++mf)
#pragma unroll
      for (int r = 0; r < 4; ++r){
        int row = mt * 128 + wr + mf * 16 + (lane >> 4) * 4 + r;
#pragma unroll
        for (int nf = 0; nf < 4; ++nf)
          qh[(size_t)row * 768 + colv[nf]] = f2bf((acc[mf][nf][r] + bzv[nf]) * zzv[nf]);
      }
  } else {
#pragma unroll
    for (int mf = 0; mf < 4; ++mf)
#pragma unroll
      for (int r = 0; r < 4; ++r){
        int row = mt * 128 + wr + mf * 16 + (lane >> 4) * 4 + r;
        int rk = rank[row];
        if (rk < 0) continue;
        int bsel = row >> 10;
        if (z == 1){
#pragma unroll
          for (int nf = 0; nf < 4; ++nf)
            kc[(size_t)(bsel * 1024 + rk) * 768 + colv[nf]] =
                f2bf((acc[mf][nf][r] + bzv[nf]) * zzv[nf]);
        } else {
#pragma unroll
          for (int nf = 0; nf < 4; ++nf){
            int hh = colv[nf] >> 6, dd = colv[nf] & 63;
            vtc[((size_t)(bsel * 12 + hh) * 64 + dd) * 1024 + rk] =
                f2bf((acc[mf][nf][r] + bzv[nf]) * zzv[nf]);
          }
        }
      }
  }
}

// ---------------------------------------------------------------------------
// Flash attention, swapped-QK^T in-register-P version.
//   S^T = mfma(K, Q): lane holds S[key = f*16 + (lane>>4)*4 + r][q = lane&15].
//   PV A-frag word j (half ks) = keys K0 = ks*32 + (destlane>>4)*8 + 2j:
//     register f = 2*ks + destbit5, src lane = (l&15) + 16*(j>>1) + 32*destbit4,
//     word = j&1.  Fetch both f-candidates via bpermute, select by own bit5.
//   P packed bf16 with BIT-EXACT manual f2bf packing (no cvt_pk asm).
// ---------------------------------------------------------------------------
__global__ __launch_bounds__(256) void attn_fwd5(
    const us* __restrict__ qh, const us* __restrict__ kc,
    const us* __restrict__ vtc, const int* __restrict__ nbd,
    us* __restrict__ ao)
{
  const int flat = blockIdx.x + 16 * blockIdx.y + 192 * blockIdx.z;
  const int xcd = flat & 7, c = flat >> 3;          // c in [0,96)
  const int pair = xcd * 6 + (c >> 4);              // [0,48)
  const int qt = c & 15, h = pair % 12, b = pair / 12;
  const int tid = threadIdx.x, lane = tid & 63, w = tid >> 6;

  const int nbv = nbd[b];
  const int nt = (nbv + 63) >> 6;

  __shared__ __align__(16) us Ks[2][64 * 64];
  __shared__ __align__(16) us Vs[2][64 * 64];

  // Q fragments straight from global: Q[w*16 + (lane&15)][ks*32 + (lane>>4)*8 ..]
  short8 qf[2];
#pragma unroll
  for (int ks = 0; ks < 2; ++ks)
    qf[ks] = *(const short8*)(qh +
              (size_t)(b * 1024 + qt * 64 + w * 16 + (lane & 15)) * 768 +
              h * 64 + ks * 32 + (lane >> 4) * 8);

  short8 kr[2], vr[2];
  auto KVLOAD = [&](int kt){
#pragma unroll
    for (int p = 0; p < 2; ++p){
      int cc = p * 256 + tid, row = cc >> 3, db = (cc & 7) * 8;
      kr[p] = *(const short8*)(kc + (size_t)(b * 1024 + kt * 64 + row) * 768 + h * 64 + db);
      vr[p] = *(const short8*)(vtc + ((size_t)((b * 12 + h) * 64 + row)) * 1024 + kt * 64 + db);
    }
  };
  auto KVWRITE = [&](int buf){
#pragma unroll
    for (int p = 0; p < 2; ++p){
      int cc = p * 256 + tid, row = cc >> 3, db = (cc & 7) * 8;
      int byte = (row * 128 + db * 2) ^ ((row & 7) << 4);
      *(short8*)((char*)Ks[buf] + byte) = kr[p];
      *(short8*)((char*)Vs[buf] + byte) = vr[p];
    }
  };
  KVLOAD(0); KVWRITE(0);
  __syncthreads();

  const int bpbase = (((lane & 16) << 1) | (lane & 15)) << 2;  // src-lane*4
  const bool hi5 = (lane & 32) != 0;

  float lsum = 0.f;
  f32x4 o[4] = {};
  int cur = 0;
  for (int kt = 0; kt < nt; ++kt){
    if (kt + 1 < nt) KVLOAD(kt + 1);

    // S^T = K Q^T  (m = key, n = q, k-dim = d)
    f32x4 s[4] = {};
#pragma unroll
    for (int ks = 0; ks < 2; ++ks)
#pragma unroll
      for (int f = 0; f < 4; ++f){
        int row = f * 16 + (lane & 15);
        short8 kf = *(const short8*)((const char*)Ks[cur] +
                    ((row * 128 + ks * 64 + (lane >> 4) * 16) ^ ((row & 7) << 4)));
        s[f] = MFMA16(kf, qf[ks], s[f]);
      }

    // p = exp(s * scale); pad keys masked only in the (uniform) tail tile
    float p_[4][4];
#pragma unroll
    for (int f = 0; f < 4; ++f)
#pragma unroll
      for (int r = 0; r < 4; ++r)
        p_[f][r] = __expf(s[f][r] * 0.125f);
    if (kt == nt - 1){
      int kb = kt * 64 + ((lane >> 4) << 2);
#pragma unroll
      for (int f = 0; f < 4; ++f)
#pragma unroll
        for (int r = 0; r < 4; ++r)
          p_[f][r] = (kb + f * 16 + r < nbv) ? p_[f][r] : 0.f;
    }
#pragma unroll
    for (int f = 0; f < 4; ++f)
      lsum += (p_[f][0] + p_[f][1]) + (p_[f][2] + p_[f][3]);

    // pack to bf16 pairs, BIT-EXACT (low half = even key, high half = odd key)
    unsigned pk[4][2];
#pragma unroll
    for (int f = 0; f < 4; ++f){
      pk[f][0] = (unsigned)f2bf(p_[f][0]) | ((unsigned)f2bf(p_[f][1]) << 16);
      pk[f][1] = (unsigned)f2bf(p_[f][2]) | ((unsigned)f2bf(p_[f][3]) << 16);
    }

    // assemble PV A-fragments: fetch both f-candidates through the permute
    // network, select by own (dest) bit5 afterwards.
    PU pa0, pa1;
#pragma unroll
    for (int j = 0; j < 4; ++j){
      int addr = bpbase + ((j & 2) << 5);
      int wsel = j & 1;
      int t0 = __builtin_amdgcn_ds_bpermute(addr, (int)pk[0][wsel]);
      int t1 = __builtin_amdgcn_ds_bpermute(addr, (int)pk[1][wsel]);
      int t2 = __builtin_amdgcn_ds_bpermute(addr, (int)pk[2][wsel]);
      int t3 = __builtin_amdgcn_ds_bpermute(addr, (int)pk[3][wsel]);
      pa0.w[j] = hi5 ? t1 : t0;
      pa1.w[j] = hi5 ? t3 : t2;
    }

    // O += P V  (m = q, n = d, k-dim = key)
#pragma unroll
    for (int df = 0; df < 4; ++df){
      int vrow = df * 16 + (lane & 15);
      short8 vb0 = *(const short8*)((const char*)Vs[cur] +
                   ((vrow * 128 + 0  + (lane >> 4) * 16) ^ ((vrow & 7) << 4)));
      short8 vb1 = *(const short8*)((const char*)Vs[cur] +
                   ((vrow * 128 + 64 + (lane >> 4) * 16) ^ ((vrow & 7) << 4)));
      o[df] = MFMA16(pa0.v, vb0, o[df]);
      o[df] = MFMA16(pa1.v, vb1, o[df]);
    }

    if (kt + 1 < nt) KVWRITE(cur ^ 1);
    __syncthreads();
    cur ^= 1;
  }

  // reduce l over the 4 lane-groups sharing q = lane&15, then fan out to the
  // output mapping q = (lane>>4)*4 + r
  float l = lsum;
  l += __shfl_xor(l, 16, 64);
  l += __shfl_xor(l, 32, 64);
  float linv[4];
#pragma unroll
  for (int r = 0; r < 4; ++r)
    linv[r] = __builtin_amdgcn_rcpf(__shfl(l, (lane >> 4) * 4 + r, 64));

#pragma unroll
  for (int df = 0; df < 4; ++df)
#pragma unroll
    for (int r = 0; r < 4; ++r){
      int qrow = qt * 64 + w * 16 + (lane >> 4) * 4 + r;
      int dcol = df * 16 + (lane & 15);
      ao[(size_t)(b * 1024 + qrow) * 768 + h * 64 + dcol] = f2bf(o[df][r] * linv[r]);
    }
}

// ---------------------------------------------------------------------------
// Output projection: depth-2 pipeline + swizzle + remap; fp32 out to [n][b][c].
// ---------------------------------------------------------------------------
__global__ __launch_bounds__(256, 2) void out_gemm4(
    const us* __restrict__ ain, const us* __restrict__ wo,
    const float* __restrict__ bo, float* __restrict__ dout)
{
  __shared__ __align__(16) us As[2][128 * 64];
  __shared__ __align__(16) us Bs[2][128 * 64];

  const int tid = threadIdx.x, lane = tid & 63, w = tid >> 6;
  const int wr = (w >> 1) * 64, wc = (w & 1) * 64;
  const int flat = blockIdx.x + blockIdx.y * 32;
  const int xcd = flat & 7, c = flat >> 3;
  const int mt = xcd * 4 + (c & 3);
  const int nt = c >> 2;

  f32x4 acc[4][4] = {};

  auto STAGE = [&](int kt, int buf){
#pragma unroll
    for (int p = 0; p < 4; ++p){
      int chunk = p * 256 + tid;
      int row = chunk >> 3;
      int colb = ((chunk & 7) ^ (row & 7)) * 8;
      GL16(ain + (size_t)(mt * 128 + row) * 768 + kt * 64 + colb,
           As[buf] + (p * 256 + w * 64) * 8);
      GL16(wo  + (size_t)(nt * 128 + row) * 768 + kt * 64 + colb,
           Bs[buf] + (p * 256 + w * 64) * 8);
    }
  };

  STAGE(0, 0);
  STAGE(1, 1);
  for (int kt = 0; kt < 12; ++kt){
    const int cur = kt & 1;
    if (kt < 11) asm volatile("s_waitcnt vmcnt(8)" ::: "memory");
    else         asm volatile("s_waitcnt vmcnt(0)" ::: "memory");
    __builtin_amdgcn_s_barrier();

#pragma unroll
    for (int ks = 0; ks < 2; ++ks){
      short8 af[4], bf4[4];
#pragma unroll
      for (int mf = 0; mf < 4; ++mf){
        int row = wr + mf * 16 + (lane & 15);
        int byte = (row * 128 + ks * 64 + (lane >> 4) * 16) ^ ((row & 7) << 4);
        af[mf] = *(const short8*)((const char*)As[cur] + byte);
      }
#pragma unroll
      for (int nf = 0; nf < 4; ++nf){
        int row = wc + nf * 16 + (lane & 15);
        int byte = (row * 128 + ks * 64 + (lane >> 4) * 16) ^ ((row & 7) << 4);
        bf4[nf] = *(const short8*)((const char*)Bs[cur] + byte);
      }
#pragma unroll
      for (int mf = 0; mf < 4; ++mf)
#pragma unroll
        for (int nf = 0; nf < 4; ++nf)
          acc[mf][nf] = MFMA16(af[mf], bf4[nf], acc[mf][nf]);
    }

    asm volatile("s_waitcnt lgkmcnt(0)" ::: "memory");
    __builtin_amdgcn_s_barrier();
    if (kt < 10) STAGE(kt + 2, cur);
  }

#pragma unroll
  for (int nf = 0; nf < 4; ++nf){
    int col = nt * 128 + wc + nf * 16 + (lane & 15);
    float bz = bo[col];
#pragma unroll
    for (int mf = 0; mf < 4; ++mf)
#pragma unroll
      for (int r = 0; r < 4; ++r){
        int row = mt * 128 + wr + mf * 16 + (lane >> 4) * 4 + r;
        int n = row & 1023, bsel = row >> 10;
        dout[(size_t)(n * 4 + bsel) * 768 + col] = acc[mf][nf][r] + bz;
      }
  }
}

extern "C" void kernel_launch(void* const* d_in, const int* in_sizes, int n_in,
                              void* d_out, int out_size, void* d_ws, size_t ws_size,
                              hipStream_t stream)
{
  const float* q    = (const float*)d_in[0];
  const float* k    = (const float*)d_in[1];
  const float* v    = (const float*)d_in[2];
  const int*   mask = (const int*)d_in[3];
  const float* Wq   = (const float*)d_in[4];
  const float* bq   = (const float*)d_in[5];
  const float* Wk   = (const float*)d_in[6];
  const float* bk   = (const float*)d_in[7];
  const float* Wv   = (const float*)d_in[8];
  const float* bv   = (const float*)d_in[9];
  const float* Wo   = (const float*)d_in[10];
  const float* bo   = (const float*)d_in[11];
  const float* zeta = (const float*)d_in[12];

  // bf16 x for q/k parked inside d_out (overwritten by final GEMM)
  us* xbq = (us*)d_out;
  us* xbk = xbq + 3145728;
  // workspace layout
  us* xbv = (us*)d_ws;
  us* wb  = xbv + 3145728;      // 4 x 768 x 768 bf16 weights
  us* qh  = wb  + 2359296;
  us* kc  = qh  + 3145728;      // compacted K rows [b*1024 + rank][768]
  us* vtc = kc  + 3145728;      // compacted V^T [b][h][d][rank]
  int* rank = (int*)(vtc + 3145728);
  int* nbd  = rank + 4096;
  us* ao = xbv;                 // reuse: xbv dead after qkv_gemm5

  prep<<<8836, 256, 0, stream>>>(q, k, v, Wq, Wk, Wv, Wo, mask,
                                 xbq, xbk, xbv, wb, (f32x4*)kc, rank, nbd);
  qkv_gemm5<<<dim3(32, 6, 3), 256, 0, stream>>>(xbq, xbk, xbv, wb, bq, bk, bv,
                                                zeta, rank, qh, kc, vtc);
  attn_fwd5<<<dim3(16, 12, 4), 256, 0, stream>>>(qh, kc, vtc, nbd, ao);
  out_gemm4<<<dim3(32, 6, 1), 256, 0, stream>>>(ao, wb + 3 * 589824, bo, (float*)d_out);
}